// Round 8
// baseline (364.617 us; speedup 1.0000x reference)
//
#include <hip/hip_runtime.h>

// irreps linear: 256x0e + 128x1o + 64x2e, shared weights, bias on 0e.
// x: (200000, 960) f32; w: 86016 f32; b: 256 f32; out: (200000, 960) f32.
//
// Round 8 = R7's pipeline shape with ONLY __syncthreads ordering (the
// R3/R4/R6-verified machinery; no raw s_barrier / counted vmcnt -> no race):
// grid (2500, 3); each block owns 5 consecutive 16-row tiles of one family.
// Per iter: issue global_load_lds staging for tile t+1 into the spare buffer,
// compute tile t from LDS (fragments+cvtpk+MFMA), ds_write outputs into the
// out-buffer (XOR swizzle), __syncthreads (orders out write->read AND drains
// staging, which had the whole compute phase to progress), unload out-buffer
// with full-line 1024B/instr global stores, __syncthreads. Stores drain at
// the NEXT iter's first sync (a compute phase later). fam1/fam2 weight frags
// live in registers. All numerics byte-identical to validated round 6.

typedef short frag8 __attribute__((ext_vector_type(8)));   // 8 bf16
typedef float f32x4 __attribute__((ext_vector_type(4)));
typedef unsigned int u32;
typedef u32 u32x4 __attribute__((ext_vector_type(4)));

#define TILE_B 61440L    // 16 rows * 3840 B

static __device__ __forceinline__ short f2bf(float f) {   // prep kernel only
    union { float f; unsigned u; } v; v.f = f;
    unsigned r = (v.u + 0x7FFFu + ((v.u >> 16) & 1u)) >> 16;  // RNE
    return (short)r;
}

static __device__ __forceinline__ u32 cvtpk(float lo, float hi) {
    u32 r;
    asm("v_cvt_pk_bf16_f32 %0, %1, %2" : "=v"(r) : "v"(lo), "v"(hi));
    return r;
}

static __device__ __forceinline__ frag8 asfrag(u32x4 u) {
    union { u32x4 u; frag8 f; } t; t.u = u; return t.f;
}

#define MFMA(a, b, c) __builtin_amdgcn_mfma_f32_16x16x32_bf16((a), (b), (c), 0, 0, 0)

// ---- weight prep: unchanged (validated rounds 1-6). frag f, lane l, reg j:
// k = 32*s + 4*(l>>4) + (j&3) + 16*(j>>2), w = nt*16 + (l&15).
__global__ __launch_bounds__(256) void prep_kernel(const float* __restrict__ w,
                                                   short* __restrict__ wf) {
    int e = blockIdx.x * 256 + threadIdx.x;   // 0..86015
    int f = e >> 9;
    int r = e & 511;
    int l = r >> 3, j = r & 7;
    int l15 = l & 15, lg = l >> 4;
    int kk = 4 * lg + (j & 3) + 16 * (j >> 2);
    int u, wc, woff, mul; float scale;
    if (f < 128) {
        int nt = f >> 3, s = f & 7;
        u = 32 * s + kk; wc = nt * 16 + l15; woff = 0;     mul = 256; scale = 0.0625f;
    } else if (f < 160) {
        int g = f - 128, nt = g >> 2, s = g & 3;
        u = 32 * s + kk; wc = nt * 16 + l15; woff = 65536; mul = 128; scale = 0.088388347648318447f;
    } else {
        int g = f - 160, nt = g >> 1, s = g & 1;
        u = 32 * s + kk; wc = nt * 16 + l15; woff = 81920; mul = 64;  scale = 0.125f;
    }
    wf[e] = f2bf(scale * w[woff + u * mul + wc]);
}

static __device__ __forceinline__ void gload_lds16(const void* g, void* l) {
    __builtin_amdgcn_global_load_lds(
        (const __attribute__((address_space(1))) unsigned int*)g,
        (__attribute__((address_space(3))) unsigned int*)l, 16, 0, 0);
}

__global__ __launch_bounds__(256) void lin_pipe(const float* __restrict__ x,
                                                const short* __restrict__ wf,
                                                const float* __restrict__ bias,
                                                float* __restrict__ out) {
    extern __shared__ __align__(16) char smem[];   // 73728 B dynamic
    const int tid  = threadIdx.x;
    const int lane = tid & 63;
    const int wv   = tid >> 6;
    const int l15  = lane & 15;
    const int lg   = lane >> 4;
    const int sw4  = (l15 & 7) << 4;
    const int fam  = blockIdx.y;
    const long tile0 = (long)blockIdx.x * 5;
    const char* __restrict__ xbase = (const char*)x;
    char* __restrict__ obase = (char*)out;
    const frag8* __restrict__ wfr = (const frag8*)wf;

    if (fam == 0) {
        // ============ family 0: cols 0..255, K=256. SZ=16384 ============
        f32x4 bv[4];
        #pragma unroll
        for (int q = 0; q < 4; ++q)
            bv[q] = *(const f32x4*)(bias + (4 * wv + q) * 16 + 4 * lg);
        {   // prologue: stage tile0 -> buf0
            const char* xb = xbase + tile0 * TILE_B;
            #pragma unroll
            for (int j = 0; j < 4; ++j) {
                int c = j * 256 + tid, r = c >> 6, g = (c & 63) ^ (r & 7);
                gload_lds16(xb + r * 3840 + (g << 4), smem + (j * 256 + wv * 64) * 16);
            }
        }
        __syncthreads();
        #pragma unroll
        for (int it = 0; it < 5; ++it) {
            const long tile = tile0 + it;
            const int cur = it & 1;
            if (it < 4) {   // issue staging for t+1 before compute
                const char* xb = xbase + (tile + 1) * TILE_B;
                char* db = smem + (cur ^ 1) * 16384;
                #pragma unroll
                for (int j = 0; j < 4; ++j) {
                    int c = j * 256 + tid, r = c >> 6, g = (c & 63) ^ (r & 7);
                    gload_lds16(xb + r * 3840 + (g << 4), db + (j * 256 + wv * 64) * 16);
                }
            }
            const char* sb = smem + cur * 16384 + l15 * 1024;
            frag8 a0[8];
            #pragma unroll
            for (int s = 0; s < 8; ++s) {
                const f32x4 v0 = *(const f32x4*)(sb + (((8 * s + lg) << 4) ^ sw4));
                const f32x4 v1 = *(const f32x4*)(sb + (((8 * s + 4 + lg) << 4) ^ sw4));
                u32x4 t = { cvtpk(v0[0], v0[1]), cvtpk(v0[2], v0[3]),
                            cvtpk(v1[0], v1[1]), cvtpk(v1[2], v1[3]) };
                a0[s] = asfrag(t);
            }
            f32x4 st[4];
            #pragma unroll
            for (int q = 0; q < 4; ++q) {
                const int nt = 4 * wv + q;
                f32x4 acc = {0.f, 0.f, 0.f, 0.f};
                #pragma unroll
                for (int s = 0; s < 8; ++s)
                    acc = MFMA(wfr[(nt * 8 + s) * 64 + lane], a0[s], acc);
                st[q] = acc + bv[q];
            }
            #pragma unroll
            for (int q = 0; q < 4; ++q) {
                const int g0 = (4 * wv + q) * 4 + lg;
                *(f32x4*)(smem + 32768 + l15 * 1024 + ((g0 ^ (l15 & 7)) << 4)) = st[q];
            }
            __syncthreads();   // out write->read order; drains staging (post-compute)
            char* ob = obase + tile * TILE_B;
            #pragma unroll
            for (int j = 0; j < 4; ++j) {
                int c = j * 256 + tid, r = c >> 6, g = c & 63;
                f32x4 v = *(const f32x4*)(smem + 32768 + r * 1024 + ((g ^ (r & 7)) << 4));
                *(f32x4*)(ob + (long)r * 3840 + (g << 4)) = v;
            }
            __syncthreads();   // out read->next write order
        }
    } else if (fam == 1) {
        // ======= family 1: cols 256..639 (col = 256+3u+i). SZ=24576 =======
        frag8 w1[8];
        #pragma unroll
        for (int q = 0; q < 2; ++q)
            #pragma unroll
            for (int s = 0; s < 4; ++s)
                w1[q * 4 + s] = wfr[(128 + (2 * wv + q) * 4 + s) * 64 + lane];
        {   // prologue
            const char* xb = xbase + tile0 * TILE_B;
            #pragma unroll
            for (int j = 0; j < 6; ++j) {
                int c = j * 256 + tid, r = c / 96, cc = c - r * 96, g = cc ^ (r & 7);
                gload_lds16(xb + r * 3840 + 1024 + (g << 4), smem + (j * 256 + wv * 64) * 16);
            }
        }
        __syncthreads();
        #pragma unroll
        for (int it = 0; it < 5; ++it) {
            const long tile = tile0 + it;
            const int cur = it & 1;
            if (it < 4) {
                const char* xb = xbase + (tile + 1) * TILE_B;
                char* db = smem + (cur ^ 1) * 24576;
                #pragma unroll
                for (int j = 0; j < 6; ++j) {
                    int c = j * 256 + tid, r = c / 96, cc = c - r * 96, g = cc ^ (r & 7);
                    gload_lds16(xb + r * 3840 + 1024 + (g << 4), db + (j * 256 + wv * 64) * 16);
                }
            }
            const char* sb = smem + cur * 24576 + l15 * 1536;
            u32x4 a1u[12];
            #pragma unroll
            for (int s = 0; s < 4; ++s) {
                #pragma unroll
                for (int h = 0; h < 2; ++h) {
                    const int cb = 24 * s + 12 * h + 3 * lg;
                    const f32x4 q0 = *(const f32x4*)(sb + ((cb << 4) ^ sw4));
                    const f32x4 q1 = *(const f32x4*)(sb + (((cb + 1) << 4) ^ sw4));
                    const f32x4 q2 = *(const f32x4*)(sb + (((cb + 2) << 4) ^ sw4));
                    a1u[0 + s][2 * h]     = cvtpk(q0[0], q0[3]);
                    a1u[0 + s][2 * h + 1] = cvtpk(q1[2], q2[1]);
                    a1u[4 + s][2 * h]     = cvtpk(q0[1], q1[0]);
                    a1u[4 + s][2 * h + 1] = cvtpk(q1[3], q2[2]);
                    a1u[8 + s][2 * h]     = cvtpk(q0[2], q1[1]);
                    a1u[8 + s][2 * h + 1] = cvtpk(q2[0], q2[3]);
                }
            }
            f32x4 sv[2][3];
            #pragma unroll
            for (int q = 0; q < 2; ++q) {
                f32x4 c0 = {0.f,0.f,0.f,0.f}, c1 = {0.f,0.f,0.f,0.f}, c2 = {0.f,0.f,0.f,0.f};
                #pragma unroll
                for (int s = 0; s < 4; ++s) {
                    frag8 bw = w1[q * 4 + s];
                    c0 = MFMA(bw, asfrag(a1u[0 + s]), c0);
                    c1 = MFMA(bw, asfrag(a1u[4 + s]), c1);
                    c2 = MFMA(bw, asfrag(a1u[8 + s]), c2);
                }
                sv[q][0] = (f32x4){c0[0], c1[0], c2[0], c0[1]};
                sv[q][1] = (f32x4){c1[1], c2[1], c0[2], c1[2]};
                sv[q][2] = (f32x4){c2[2], c0[3], c1[3], c2[3]};
            }
            #pragma unroll
            for (int q = 0; q < 2; ++q) {
                const int g0 = 3 * ((2 * wv + q) * 4 + lg);
                char* wb = smem + 49152 + l15 * 1536;
                #pragma unroll
                for (int i = 0; i < 3; ++i)
                    *(f32x4*)(wb + (((g0 + i) ^ (l15 & 7)) << 4)) = sv[q][i];
            }
            __syncthreads();
            char* ob = obase + tile * TILE_B;
            #pragma unroll
            for (int j = 0; j < 6; ++j) {
                int c = j * 256 + tid, r = c / 96, g = c - r * 96;
                f32x4 v = *(const f32x4*)(smem + 49152 + r * 1536 + ((g ^ (r & 7)) << 4));
                *(f32x4*)(ob + (long)r * 3840 + 1024 + (g << 4)) = v;
            }
            __syncthreads();
        }
    } else {
        // ======= family 2: cols 640..959 (col = 640+5u+i). SZ=20480 =======
        frag8 w2[2];
        #pragma unroll
        for (int s = 0; s < 2; ++s)
            w2[s] = wfr[(160 + wv * 2 + s) * 64 + lane];
        {   // prologue
            const char* xb = xbase + tile0 * TILE_B;
            #pragma unroll
            for (int j = 0; j < 5; ++j) {
                int c = j * 256 + tid, r = c / 80, cc = c - r * 80, g = cc ^ (r & 7);
                gload_lds16(xb + r * 3840 + 2560 + (g << 4), smem + (j * 256 + wv * 64) * 16);
            }
        }
        __syncthreads();
        #pragma unroll
        for (int it = 0; it < 5; ++it) {
            const long tile = tile0 + it;
            const int cur = it & 1;
            if (it < 4) {
                const char* xb = xbase + (tile + 1) * TILE_B;
                char* db = smem + (cur ^ 1) * 20480;
                #pragma unroll
                for (int j = 0; j < 5; ++j) {
                    int c = j * 256 + tid, r = c / 80, cc = c - r * 80, g = cc ^ (r & 7);
                    gload_lds16(xb + r * 3840 + 2560 + (g << 4), db + (j * 256 + wv * 64) * 16);
                }
            }
            const char* sb = smem + cur * 20480 + l15 * 1280;
            u32x4 a2u[10];
            #pragma unroll
            for (int s = 0; s < 2; ++s) {
                #pragma unroll
                for (int h = 0; h < 2; ++h) {
                    const int cb = 40 * s + 20 * h + 5 * lg;
                    const f32x4 q0 = *(const f32x4*)(sb + ((cb << 4) ^ sw4));
                    const f32x4 q1 = *(const f32x4*)(sb + (((cb + 1) << 4) ^ sw4));
                    const f32x4 q2 = *(const f32x4*)(sb + (((cb + 2) << 4) ^ sw4));
                    const f32x4 q3 = *(const f32x4*)(sb + (((cb + 3) << 4) ^ sw4));
                    const f32x4 q4 = *(const f32x4*)(sb + (((cb + 4) << 4) ^ sw4));
                    a2u[0 + s][2 * h]     = cvtpk(q0[0], q1[1]);
                    a2u[0 + s][2 * h + 1] = cvtpk(q2[2], q3[3]);
                    a2u[2 + s][2 * h]     = cvtpk(q0[1], q1[2]);
                    a2u[2 + s][2 * h + 1] = cvtpk(q2[3], q4[0]);
                    a2u[4 + s][2 * h]     = cvtpk(q0[2], q1[3]);
                    a2u[4 + s][2 * h + 1] = cvtpk(q3[0], q4[1]);
                    a2u[6 + s][2 * h]     = cvtpk(q0[3], q2[0]);
                    a2u[6 + s][2 * h + 1] = cvtpk(q3[1], q4[2]);
                    a2u[8 + s][2 * h]     = cvtpk(q1[0], q2[1]);
                    a2u[8 + s][2 * h + 1] = cvtpk(q3[2], q4[3]);
                }
            }
            f32x4 sv[5];
            {
                f32x4 c0 = {0.f,0.f,0.f,0.f}, c1 = {0.f,0.f,0.f,0.f}, c2 = {0.f,0.f,0.f,0.f},
                      c3 = {0.f,0.f,0.f,0.f}, c4 = {0.f,0.f,0.f,0.f};
                #pragma unroll
                for (int s = 0; s < 2; ++s) {
                    frag8 bw = w2[s];
                    c0 = MFMA(bw, asfrag(a2u[0 + s]), c0);
                    c1 = MFMA(bw, asfrag(a2u[2 + s]), c1);
                    c2 = MFMA(bw, asfrag(a2u[4 + s]), c2);
                    c3 = MFMA(bw, asfrag(a2u[6 + s]), c3);
                    c4 = MFMA(bw, asfrag(a2u[8 + s]), c4);
                }
                sv[0] = (f32x4){c0[0], c1[0], c2[0], c3[0]};
                sv[1] = (f32x4){c4[0], c0[1], c1[1], c2[1]};
                sv[2] = (f32x4){c3[1], c4[1], c0[2], c1[2]};
                sv[3] = (f32x4){c2[2], c3[2], c4[2], c0[3]};
                sv[4] = (f32x4){c1[3], c2[3], c3[3], c4[3]};
            }
            {
                const int g0 = 5 * (wv * 4 + lg);
                char* wb = smem + 40960 + l15 * 1280;
                #pragma unroll
                for (int i = 0; i < 5; ++i)
                    *(f32x4*)(wb + (((g0 + i) ^ (l15 & 7)) << 4)) = sv[i];
            }
            __syncthreads();
            char* ob = obase + tile * TILE_B;
            #pragma unroll
            for (int j = 0; j < 5; ++j) {
                int c = j * 256 + tid, r = c / 80, g = c - r * 80;
                f32x4 v = *(const f32x4*)(smem + 40960 + r * 1280 + ((g ^ (r & 7)) << 4));
                *(f32x4*)(ob + (long)r * 3840 + 2560 + (g << 4)) = v;
            }
            __syncthreads();
        }
    }
}

extern "C" void kernel_launch(void* const* d_in, const int* in_sizes, int n_in,
                              void* d_out, int out_size, void* d_ws, size_t ws_size,
                              hipStream_t stream) {
    const float* x = (const float*)d_in[0];
    const float* w = (const float*)d_in[1];
    const float* b = (const float*)d_in[2];
    float* out = (float*)d_out;
    short* wf  = (short*)d_ws;          // 86016 bf16 = 172032 B of scratch

    hipLaunchKernelGGL(prep_kernel, dim3(336), dim3(256), 0, stream, w, wf);

    (void)hipFuncSetAttribute((const void*)lin_pipe,
                              hipFuncAttributeMaxDynamicSharedMemorySize, 73728);
    // 12500 tiles = 2500 blocks x 5 tiles, x 3 irrep families
    hipLaunchKernelGGL(lin_pipe, dim3(2500, 3), dim3(256), 73728, stream,
                       x, wf, b, out);
}

// Round 9
// 359.006 us; speedup vs baseline: 1.0156x; 1.0156x over previous
//
#include <hip/hip_runtime.h>

// irreps linear: 256x0e + 128x1o + 64x2e, shared weights, bias on 0e.
// x: (200000, 960) f32; w: 86016 f32; b: 256 f32; out: (200000, 960) f32.
//
// Round 9: three per-family kernels, R6 phase structure (stage -> sync ->
// frags+MFMA -> sync -> LDS out pieces -> sync -> full-line stores), with the
// XOR chunk swizzle REPLACED by +16B padded LDS row stride (same optimal
// b128 banking: quad=(row+chunk)%8 uniform; verified for all patterns), which
// lets global_load_lds stage ONE ROW PER INSTRUCTION from pristine contiguous
// global addresses (no 16B-granule gather). fam1/fam2 row tails staged with
// exec-masked partial-wave instructions. Per-family LDS 16.6/24.8/20.7 KB ->
// 9/6/7 blocks/CU. All fragment/output content maps byte-identical to R6.

typedef short frag8 __attribute__((ext_vector_type(8)));   // 8 bf16
typedef float f32x4 __attribute__((ext_vector_type(4)));
typedef unsigned int u32;
typedef u32 u32x4 __attribute__((ext_vector_type(4)));

#define ST0 1040   // 65 chunks * 16B (64 data + 1 pad)
#define ST1 1552   // 97 chunks
#define ST2 1296   // 81 chunks

static __device__ __forceinline__ short f2bf(float f) {   // prep kernel only
    union { float f; unsigned u; } v; v.f = f;
    unsigned r = (v.u + 0x7FFFu + ((v.u >> 16) & 1u)) >> 16;  // RNE
    return (short)r;
}

static __device__ __forceinline__ u32 cvtpk(float lo, float hi) {
    u32 r;
    asm("v_cvt_pk_bf16_f32 %0, %1, %2" : "=v"(r) : "v"(lo), "v"(hi));
    return r;
}

static __device__ __forceinline__ frag8 asfrag(u32x4 u) {
    union { u32x4 u; frag8 f; } t; t.u = u; return t.f;
}

#define MFMA(a, b, c) __builtin_amdgcn_mfma_f32_16x16x32_bf16((a), (b), (c), 0, 0, 0)

// ---- weight prep: unchanged (validated rounds 1-8). frag f, lane l, reg j:
// k = 32*s + 4*(l>>4) + (j&3) + 16*(j>>2), w = nt*16 + (l&15).
__global__ __launch_bounds__(256) void prep_kernel(const float* __restrict__ w,
                                                   short* __restrict__ wf) {
    int e = blockIdx.x * 256 + threadIdx.x;   // 0..86015
    int f = e >> 9;
    int r = e & 511;
    int l = r >> 3, j = r & 7;
    int l15 = l & 15, lg = l >> 4;
    int kk = 4 * lg + (j & 3) + 16 * (j >> 2);
    int u, wc, woff, mul; float scale;
    if (f < 128) {
        int nt = f >> 3, s = f & 7;
        u = 32 * s + kk; wc = nt * 16 + l15; woff = 0;     mul = 256; scale = 0.0625f;
    } else if (f < 160) {
        int g = f - 128, nt = g >> 2, s = g & 3;
        u = 32 * s + kk; wc = nt * 16 + l15; woff = 65536; mul = 128; scale = 0.088388347648318447f;
    } else {
        int g = f - 160, nt = g >> 1, s = g & 1;
        u = 32 * s + kk; wc = nt * 16 + l15; woff = 81920; mul = 64;  scale = 0.125f;
    }
    wf[e] = f2bf(scale * w[woff + u * mul + wc]);
}

static __device__ __forceinline__ void gload_lds16(const void* g, void* l) {
    __builtin_amdgcn_global_load_lds(
        (const __attribute__((address_space(1))) unsigned int*)g,
        (__attribute__((address_space(3))) unsigned int*)l, 16, 0, 0);
}

// ==================== family 0: cols 0..255, K=256 ====================
__global__ __launch_bounds__(256) void lin_f0(const float* __restrict__ x,
                                              const short* __restrict__ wf,
                                              const float* __restrict__ bias,
                                              float* __restrict__ out) {
    __shared__ __align__(16) char smem[16 * ST0];
    const int tid = threadIdx.x, lane = tid & 63, wv = tid >> 6;
    const int l15 = lane & 15, lg = lane >> 4;
    const long rowbase = (long)blockIdx.x * 16;
    const char* __restrict__ xb = (const char*)x + rowbase * 3840;
    char* __restrict__ ob = (char*)out + rowbase * 3840;
    const frag8* __restrict__ wfr = (const frag8*)wf;

    // stage: one full 1KB row per instruction, contiguous global source
    #pragma unroll
    for (int r4 = 0; r4 < 4; ++r4) {
        int r = 4 * wv + r4;
        gload_lds16(xb + (long)r * 3840 + (long)lane * 16, smem + r * ST0);
    }
    __syncthreads();   // drains vmcnt(0)

    const char* sb = smem + l15 * ST0;
    frag8 a0[8];
    #pragma unroll
    for (int s = 0; s < 8; ++s) {
        const f32x4 v0 = *(const f32x4*)(sb + (8 * s + lg) * 16);
        const f32x4 v1 = *(const f32x4*)(sb + (8 * s + 4 + lg) * 16);
        u32x4 t = { cvtpk(v0[0], v0[1]), cvtpk(v0[2], v0[3]),
                    cvtpk(v1[0], v1[1]), cvtpk(v1[2], v1[3]) };
        a0[s] = asfrag(t);
    }
    f32x4 st[4];
    #pragma unroll
    for (int q = 0; q < 4; ++q) {
        const int nt = 4 * wv + q;
        f32x4 acc = {0.f, 0.f, 0.f, 0.f};
        #pragma unroll
        for (int s = 0; s < 8; ++s)
            acc = MFMA(wfr[(nt * 8 + s) * 64 + lane], a0[s], acc);
        const f32x4 bv = *(const f32x4*)(bias + nt * 16 + 4 * lg);
        st[q] = acc + bv;
    }
    __syncthreads();   // all frag reads done; reuse smem as out buffer
    #pragma unroll
    for (int q = 0; q < 4; ++q) {
        const int g0 = (4 * wv + q) * 4 + lg;        // chunk 0..63
        *(f32x4*)(smem + l15 * ST0 + g0 * 16) = st[q];
    }
    __syncthreads();
    #pragma unroll
    for (int j = 0; j < 4; ++j) {
        int c = j * 256 + tid, r = c >> 6, g = c & 63;
        f32x4 v = *(const f32x4*)(smem + r * ST0 + g * 16);
        *(f32x4*)(ob + (long)r * 3840 + g * 16) = v;
    }
}

// ============ family 1: cols 256..639 (col = 256+3u+i), K=128 ============
__global__ __launch_bounds__(256) void lin_f1(const float* __restrict__ x,
                                              const short* __restrict__ wf,
                                              float* __restrict__ out) {
    __shared__ __align__(16) char smem[16 * ST1];
    const int tid = threadIdx.x, lane = tid & 63, wv = tid >> 6;
    const int l15 = lane & 15, lg = lane >> 4;
    const long rowbase = (long)blockIdx.x * 16;
    const char* __restrict__ xb = (const char*)x + rowbase * 3840;
    char* __restrict__ ob = (char*)out + rowbase * 3840;
    const frag8* __restrict__ wfr = (const frag8*)wf;

    frag8 w1[8];
    #pragma unroll
    for (int q = 0; q < 2; ++q)
        #pragma unroll
        for (int s = 0; s < 4; ++s)
            w1[q * 4 + s] = wfr[(128 + (2 * wv + q) * 4 + s) * 64 + lane];

    // stage rows 4wv..4wv+3: 1024B full-wave + 512B half-wave per row
    #pragma unroll
    for (int r4 = 0; r4 < 4; ++r4) {
        int r = 4 * wv + r4;
        gload_lds16(xb + (long)r * 3840 + 1024 + (long)lane * 16, smem + r * ST1);
        if (lane < 32)
            gload_lds16(xb + (long)r * 3840 + 2048 + (long)lane * 16,
                        smem + r * ST1 + 1024);
    }
    __syncthreads();

    const char* sb = smem + l15 * ST1;
    u32x4 a1u[12];
    #pragma unroll
    for (int s = 0; s < 4; ++s) {
        #pragma unroll
        for (int h = 0; h < 2; ++h) {
            const int cb = 24 * s + 12 * h + 3 * lg;
            const f32x4 q0 = *(const f32x4*)(sb + (cb    ) * 16);
            const f32x4 q1 = *(const f32x4*)(sb + (cb + 1) * 16);
            const f32x4 q2 = *(const f32x4*)(sb + (cb + 2) * 16);
            a1u[0 + s][2 * h]     = cvtpk(q0[0], q0[3]);
            a1u[0 + s][2 * h + 1] = cvtpk(q1[2], q2[1]);
            a1u[4 + s][2 * h]     = cvtpk(q0[1], q1[0]);
            a1u[4 + s][2 * h + 1] = cvtpk(q1[3], q2[2]);
            a1u[8 + s][2 * h]     = cvtpk(q0[2], q1[1]);
            a1u[8 + s][2 * h + 1] = cvtpk(q2[0], q2[3]);
        }
    }
    f32x4 sv[2][3];
    #pragma unroll
    for (int q = 0; q < 2; ++q) {
        f32x4 c0 = {0.f,0.f,0.f,0.f}, c1 = {0.f,0.f,0.f,0.f}, c2 = {0.f,0.f,0.f,0.f};
        #pragma unroll
        for (int s = 0; s < 4; ++s) {
            frag8 bw = w1[q * 4 + s];
            c0 = MFMA(bw, asfrag(a1u[0 + s]), c0);
            c1 = MFMA(bw, asfrag(a1u[4 + s]), c1);
            c2 = MFMA(bw, asfrag(a1u[8 + s]), c2);
        }
        sv[q][0] = (f32x4){c0[0], c1[0], c2[0], c0[1]};
        sv[q][1] = (f32x4){c1[1], c2[1], c0[2], c1[2]};
        sv[q][2] = (f32x4){c2[2], c0[3], c1[3], c2[3]};
    }
    __syncthreads();
    #pragma unroll
    for (int q = 0; q < 2; ++q) {
        const int g0 = 3 * ((2 * wv + q) * 4 + lg);   // chunk 0..93
        #pragma unroll
        for (int i = 0; i < 3; ++i)
            *(f32x4*)(smem + l15 * ST1 + (g0 + i) * 16) = sv[q][i];
    }
    __syncthreads();
    #pragma unroll
    for (int j = 0; j < 6; ++j) {
        int c = j * 256 + tid, r = c / 96, g = c - r * 96;
        f32x4 v = *(const f32x4*)(smem + r * ST1 + g * 16);
        *(f32x4*)(ob + (long)r * 3840 + 1024 + g * 16) = v;
    }
}

// ============ family 2: cols 640..959 (col = 640+5u+i), K=64 ============
__global__ __launch_bounds__(256) void lin_f2(const float* __restrict__ x,
                                              const short* __restrict__ wf,
                                              float* __restrict__ out) {
    __shared__ __align__(16) char smem[16 * ST2];
    const int tid = threadIdx.x, lane = tid & 63, wv = tid >> 6;
    const int l15 = lane & 15, lg = lane >> 4;
    const long rowbase = (long)blockIdx.x * 16;
    const char* __restrict__ xb = (const char*)x + rowbase * 3840;
    char* __restrict__ ob = (char*)out + rowbase * 3840;
    const frag8* __restrict__ wfr = (const frag8*)wf;

    frag8 w2[2];
    #pragma unroll
    for (int s = 0; s < 2; ++s)
        w2[s] = wfr[(160 + wv * 2 + s) * 64 + lane];

    // stage rows 4wv..4wv+3: 1024B full-wave + 256B quarter-wave per row
    #pragma unroll
    for (int r4 = 0; r4 < 4; ++r4) {
        int r = 4 * wv + r4;
        gload_lds16(xb + (long)r * 3840 + 2560 + (long)lane * 16, smem + r * ST2);
        if (lane < 16)
            gload_lds16(xb + (long)r * 3840 + 3584 + (long)lane * 16,
                        smem + r * ST2 + 1024);
    }
    __syncthreads();

    const char* sb = smem + l15 * ST2;
    u32x4 a2u[10];
    #pragma unroll
    for (int s = 0; s < 2; ++s) {
        #pragma unroll
        for (int h = 0; h < 2; ++h) {
            const int cb = 40 * s + 20 * h + 5 * lg;
            const f32x4 q0 = *(const f32x4*)(sb + (cb    ) * 16);
            const f32x4 q1 = *(const f32x4*)(sb + (cb + 1) * 16);
            const f32x4 q2 = *(const f32x4*)(sb + (cb + 2) * 16);
            const f32x4 q3 = *(const f32x4*)(sb + (cb + 3) * 16);
            const f32x4 q4 = *(const f32x4*)(sb + (cb + 4) * 16);
            a2u[0 + s][2 * h]     = cvtpk(q0[0], q1[1]);
            a2u[0 + s][2 * h + 1] = cvtpk(q2[2], q3[3]);
            a2u[2 + s][2 * h]     = cvtpk(q0[1], q1[2]);
            a2u[2 + s][2 * h + 1] = cvtpk(q2[3], q4[0]);
            a2u[4 + s][2 * h]     = cvtpk(q0[2], q1[3]);
            a2u[4 + s][2 * h + 1] = cvtpk(q3[0], q4[1]);
            a2u[6 + s][2 * h]     = cvtpk(q0[3], q2[0]);
            a2u[6 + s][2 * h + 1] = cvtpk(q3[1], q4[2]);
            a2u[8 + s][2 * h]     = cvtpk(q1[0], q2[1]);
            a2u[8 + s][2 * h + 1] = cvtpk(q3[2], q4[3]);
        }
    }
    f32x4 sv[5];
    {
        f32x4 c0 = {0.f,0.f,0.f,0.f}, c1 = {0.f,0.f,0.f,0.f}, c2 = {0.f,0.f,0.f,0.f},
              c3 = {0.f,0.f,0.f,0.f}, c4 = {0.f,0.f,0.f,0.f};
        #pragma unroll
        for (int s = 0; s < 2; ++s) {
            frag8 bw = w2[s];
            c0 = MFMA(bw, asfrag(a2u[0 + s]), c0);
            c1 = MFMA(bw, asfrag(a2u[2 + s]), c1);
            c2 = MFMA(bw, asfrag(a2u[4 + s]), c2);
            c3 = MFMA(bw, asfrag(a2u[6 + s]), c3);
            c4 = MFMA(bw, asfrag(a2u[8 + s]), c4);
        }
        sv[0] = (f32x4){c0[0], c1[0], c2[0], c3[0]};
        sv[1] = (f32x4){c4[0], c0[1], c1[1], c2[1]};
        sv[2] = (f32x4){c3[1], c4[1], c0[2], c1[2]};
        sv[3] = (f32x4){c2[2], c3[2], c4[2], c0[3]};
        sv[4] = (f32x4){c1[3], c2[3], c3[3], c4[3]};
    }
    __syncthreads();
    {
        const int g0 = 5 * (wv * 4 + lg);             // chunk 0..75
        #pragma unroll
        for (int i = 0; i < 5; ++i)
            *(f32x4*)(smem + l15 * ST2 + (g0 + i) * 16) = sv[i];
    }
    __syncthreads();
    #pragma unroll
    for (int j = 0; j < 5; ++j) {
        int c = j * 256 + tid, r = c / 80, g = c - r * 80;
        f32x4 v = *(const f32x4*)(smem + r * ST2 + g * 16);
        *(f32x4*)(ob + (long)r * 3840 + 2560 + g * 16) = v;
    }
}

extern "C" void kernel_launch(void* const* d_in, const int* in_sizes, int n_in,
                              void* d_out, int out_size, void* d_ws, size_t ws_size,
                              hipStream_t stream) {
    const float* x = (const float*)d_in[0];
    const float* w = (const float*)d_in[1];
    const float* b = (const float*)d_in[2];
    float* out = (float*)d_out;
    short* wf  = (short*)d_ws;          // 86016 bf16 = 172032 B of scratch

    hipLaunchKernelGGL(prep_kernel, dim3(336), dim3(256), 0, stream, w, wf);
    hipLaunchKernelGGL(lin_f0, dim3(12500), dim3(256), 0, stream, x, wf, b, out);
    hipLaunchKernelGGL(lin_f1, dim3(12500), dim3(256), 0, stream, x, wf, out);
    hipLaunchKernelGGL(lin_f2, dim3(12500), dim3(256), 0, stream, x, wf, out);
}